// Round 22
// baseline (2146.412 us; speedup 1.0000x reference)
//
#include <hip/hip_runtime.h>
#include <hip/hip_bf16.h>

#define L_ 8
#define H_ 16
#define D_ 1024
#define HD_ 64
#define F_ 4096
#define B_ 2
#define S_ 2048
#define NTOK (B_*S_)

typedef unsigned short u16;
typedef __bf16 bf16x8 __attribute__((ext_vector_type(8)));
typedef float f32x4 __attribute__((ext_vector_type(4)));

__device__ __forceinline__ u16 f2b(float f){ union{float f; unsigned u;} c; c.f = f; unsigned u = c.u; return (u16)((u + 0x7fffu + ((u>>16)&1u)) >> 16); }
__device__ __forceinline__ u16 f2b_fast(float f){ union{float f; unsigned u;} c; c.f = f; return (u16)((c.u + 0x8000u) >> 16); }
__device__ __forceinline__ float b2f(u16 x){ union{unsigned u; float f;} c; c.u = ((unsigned)x)<<16; return c.f; }

__device__ __forceinline__ void gload16(const u16* g, u16* l){
  __builtin_amdgcn_global_load_lds(
      (const __attribute__((address_space(1))) void*)g,
      (__attribute__((address_space(3))) void*)l,
      16 /*bytes*/, 0 /*offset*/, 0 /*aux*/);
}

__device__ __forceinline__ void lds_fence(){
  asm volatile("s_waitcnt lgkmcnt(0)" ::: "memory");
  __builtin_amdgcn_sched_barrier(0);
}

// counted-vmcnt wait + raw barrier (NOT __syncthreads: that drains vmcnt(0))
#define WAITV_BAR(n) do { \
  asm volatile("s_waitcnt vmcnt(%0)" :: "i"(n) : "memory"); \
  __builtin_amdgcn_sched_barrier(0); \
  __builtin_amdgcn_s_barrier(); \
} while(0)

// ---------------- block reduce (256 threads, 4 waves) ----------------
__device__ __forceinline__ void blk_reduce2(float& a, float& b, float* sm){
  for (int off=32; off>0; off>>=1){ a += __shfl_down(a,off); b += __shfl_down(b,off); }
  int w = threadIdx.x>>6, ln = threadIdx.x&63;
  if (ln==0){ sm[w]=a; sm[4+w]=b; }
  __syncthreads();
  a = sm[0]+sm[1]+sm[2]+sm[3];
  b = sm[4]+sm[5]+sm[6]+sm[7];
}

// ---------------- embedding + LN -> x (f32), float4 path ----------------
__global__ __launch_bounds__(256) void embed_ln(const int* __restrict__ ids,
    const float* __restrict__ tok, const float* __restrict__ pos,
    const float* __restrict__ g, const float* __restrict__ bb,
    float* __restrict__ x)
{
  __shared__ float sm[8];
  int row = blockIdx.x;
  int s   = row % S_;
  int id  = ids[row];
  int d0  = threadIdx.x*4;
  float4 t4 = *(const float4*)(tok + (size_t)id*D_ + d0);
  float4 p4 = *(const float4*)(pos + (size_t)s *D_ + d0);
  float4 v; v.x=t4.x+p4.x; v.y=t4.y+p4.y; v.z=t4.z+p4.z; v.w=t4.w+p4.w;
  float sum = (v.x+v.y)+(v.z+v.w);
  float sq  = v.x*v.x+v.y*v.y+v.z*v.z+v.w*v.w;
  blk_reduce2(sum, sq, sm);
  float mean = sum * (1.0f/D_);
  float var  = sq  * (1.0f/D_) - mean*mean;
  float inv  = rsqrtf(var + 1e-5f);
  float4 g4 = *(const float4*)(g + d0);
  float4 b4 = *(const float4*)(bb + d0);
  float4 o; o.x=(v.x-mean)*inv*g4.x+b4.x; o.y=(v.y-mean)*inv*g4.y+b4.y;
            o.z=(v.z-mean)*inv*g4.z+b4.z; o.w=(v.w-mean)*inv*g4.w+b4.w;
  *(float4*)(x + (size_t)row*D_ + d0) = o;
}

// ---------------- LN: x (f32) -> h (bf16), float4 path ----------------
__global__ __launch_bounds__(256) void ln_f32_bf16(const float* __restrict__ x,
    const float* __restrict__ g, const float* __restrict__ bb, u16* __restrict__ out)
{
  __shared__ float sm[8];
  int row = blockIdx.x;
  int d0  = threadIdx.x*4;
  float4 v = *(const float4*)(x + (size_t)row*D_ + d0);
  float sum = (v.x+v.y)+(v.z+v.w);
  float sq  = v.x*v.x+v.y*v.y+v.z*v.z+v.w*v.w;
  blk_reduce2(sum, sq, sm);
  float mean = sum * (1.0f/D_);
  float var  = sq  * (1.0f/D_) - mean*mean;
  float inv  = rsqrtf(var + 1e-5f);
  float4 g4 = *(const float4*)(g + d0);
  float4 b4 = *(const float4*)(bb + d0);
  uint2 w;
  w.x = (unsigned)f2b((v.x-mean)*inv*g4.x+b4.x) | ((unsigned)f2b((v.y-mean)*inv*g4.y+b4.y)<<16);
  w.y = (unsigned)f2b((v.z-mean)*inv*g4.z+b4.z) | ((unsigned)f2b((v.w-mean)*inv*g4.w+b4.w)<<16);
  *(uint2*)(out + (size_t)row*D_ + d0) = w;
}

// ---------------- unified weight repack: all 4 per-layer f32->bf16 transposes ----------------
__global__ __launch_bounds__(256) void repack_all(
    const float* __restrict__ Wq, const float* __restrict__ Wk, const float* __restrict__ Wv,
    const float* __restrict__ Wo, const float* __restrict__ W1, const float* __restrict__ W2,
    u16* __restrict__ wqkvt, u16* __restrict__ wot, u16* __restrict__ w1t, u16* __restrict__ w2t,
    int layer)
{
  __shared__ u16 tile[64*64];
  const int n = blockIdx.x;
  const float* src; u16* dst; int R, C, bx, by;
  if (n < 768){
    int z = n >> 4, xt = n & 15;
    int which = z >> 4, h = z & 15;
    const float* W = (which==0) ? Wq : (which==1) ? Wk : Wv;
    src = W + ((size_t)(layer*H_ + h))*D_*HD_;
    dst = wqkvt + (size_t)(which*1024 + h*64)*D_;
    R = 1024; C = 64; bx = 0; by = xt;
  } else if (n < 1024){
    int q = n - 768;  bx = q & 15; by = q >> 4;
    src = Wo + (size_t)layer*D_*D_;  dst = wot;  R = 1024; C = 1024;
  } else if (n < 2048){
    int q = n - 1024; bx = q & 63; by = q >> 6;
    src = W1 + (size_t)layer*D_*F_;  dst = w1t;  R = 1024; C = 4096;
  } else {
    int q = n - 2048; bx = q & 15; by = q >> 4;
    src = W2 + (size_t)layer*F_*D_;  dst = w2t;  R = 4096; C = 1024;
  }
  int c0 = bx*64, r0 = by*64;
  int t = threadIdx.x;
  #pragma unroll
  for (int i=0;i<2;i++){
    int idx = t + i*256;
    int row = idx>>3, c8 = idx&7;
    const float* p = src + (size_t)(r0+row)*C + c0 + c8*8;
    float4 a = *(const float4*)p;
    float4 b = *(const float4*)(p+4);
    u16 tmp[8];
    tmp[0]=f2b(a.x); tmp[1]=f2b(a.y); tmp[2]=f2b(a.z); tmp[3]=f2b(a.w);
    tmp[4]=f2b(b.x); tmp[5]=f2b(b.y); tmp[6]=f2b(b.z); tmp[7]=f2b(b.w);
    int sw = (row&7) ^ ((row>>3)&7);
    *(uint4*)(&tile[row*64 + ((c8 ^ sw)<<3)]) = *(uint4*)tmp;
  }
  __syncthreads();
  #pragma unroll
  for (int i=0;i<2;i++){
    int idx = t + i*256;
    int oc = idx>>3, tc = idx&7;
    u16 tmp[8];
    #pragma unroll
    for (int j=0;j<8;j++){
      int rr = tc*8 + j;
      int sw = (rr&7) ^ ((rr>>3)&7);
      tmp[j] = tile[rr*64 + ((((oc>>3) ^ sw)<<3) | (oc&7))];
    }
    *(uint4*)(dst + (size_t)(c0+oc)*R + r0 + tc*8) = *(uint4*)tmp;
  }
}

// ---------------- epilogue helper ----------------
__device__ __forceinline__ void epi_store(float v0,float v1,float v2,float v3,
    float* xres, u16* obf, size_t idx, int epi)
{
  if (epi==1){
    float4 t = *(float4*)(xres + idx);
    t.x += v0; t.y += v1; t.z += v2; t.w += v3;
    *(float4*)(xres + idx) = t;
  } else {
    if (epi==2){
      #define GELU_T(v) { float t2=(v)*(v); float u=(v)*fmaf(t2,0.044715f,1.0f); \
                          float e=exp2f(u*-2.3022082f); (v)=(v)*__builtin_amdgcn_rcpf(1.0f+e); }
      GELU_T(v0); GELU_T(v1); GELU_T(v2); GELU_T(v3);
      #undef GELU_T
    }
    uint2 w;
    w.x = (unsigned)f2b_fast(v0) | ((unsigned)f2b_fast(v1) << 16);
    w.y = (unsigned)f2b_fast(v2) | ((unsigned)f2b_fast(v3) << 16);
    *(uint2*)(obf + idx) = w;
  }
}

// ---------------- GEMM 64x128 tile (4 waves of 32x64): residual += A*Bt^T + bias ----------------
__global__ __launch_bounds__(256) void gemm_64x128(
    const u16* __restrict__ A, const u16* __restrict__ Bt,
    const float* __restrict__ bias0, float* __restrict__ xres,
    int M, int N, int K)
{
  __shared__ u16 As[64*64];     //  8 KB
  __shared__ u16 Bs[128*64];    // 16 KB
  const int tid = threadIdx.x;
  const int nbx = gridDim.x;
  const int nwg = nbx * gridDim.y;
  int bid = blockIdx.x + nbx*blockIdx.y;
  int nid = (bid & 7)*(nwg >> 3) + (bid >> 3);
  const int bm = (nid % nbx) * 64;
  const int bn = (nid / nbx) * 128;
  const int wv = tid>>6, ln = tid&63;
  const int wr = wv>>1, wc = wv&1;
  const int l15 = ln&15, lhi = ln>>4;
  const int l8 = ln>>3;
  const int c8s = (ln&7) ^ l8;
  f32x4 acc[2][4];
  const f32x4 zero4 = {0.f,0.f,0.f,0.f};
  #pragma unroll
  for (int i=0;i<2;i++)
    #pragma unroll
    for (int j=0;j<4;j++) acc[i][j] = zero4;

  for (int k0 = 0; k0 < K; k0 += 64) {
    #pragma unroll
    for (int i=0;i<2;i++){
      int row = wv*16 + i*8 + l8;
      gload16(A + (size_t)(bm+row)*K + k0 + c8s*8, &As[(wv*16 + i*8)*64]);
    }
    #pragma unroll
    for (int i=0;i<4;i++){
      int row = wv*32 + i*8 + l8;
      gload16(Bt + (size_t)(bn+row)*K + k0 + c8s*8, &Bs[(wv*32 + i*8)*64]);
    }
    __syncthreads();
    #pragma unroll
    for (int ks=0; ks<2; ks++){
      bf16x8 af[2], bfr[4];
      #pragma unroll
      for (int i=0;i<2;i++){
        int ra = wr*32 + i*16 + l15;
        af[i]  = *(const bf16x8*)(&As[ra*64 + (((ks*4+lhi) ^ (ra&7))<<3)]);
      }
      #pragma unroll
      for (int j=0;j<4;j++){
        int rb = wc*64 + j*16 + l15;
        bfr[j] = *(const bf16x8*)(&Bs[rb*64 + (((ks*4+lhi) ^ (rb&7))<<3)]);
      }
      #pragma unroll
      for (int i=0;i<2;i++)
        #pragma unroll
        for (int j=0;j<4;j++)
          acc[i][j] = __builtin_amdgcn_mfma_f32_16x16x32_bf16(bfr[j], af[i], acc[i][j], 0,0,0);
    }
    __syncthreads();
  }

  #pragma unroll
  for (int j=0;j<4;j++){
    int col0 = bn + wc*64 + j*16 + lhi*4;
    float4 bv4 = *(const float4*)(bias0 + col0);
    #pragma unroll
    for (int i=0;i<2;i++){
      int row = bm + wr*32 + i*16 + l15;
      size_t idx = (size_t)row*N + col0;
      float4 t = *(float4*)(xres + idx);
      t.x += acc[i][j][0] + bv4.x;
      t.y += acc[i][j][1] + bv4.y;
      t.z += acc[i][j][2] + bv4.z;
      t.w += acc[i][j][3] + bv4.w;
      *(float4*)(xres + idx) = t;
    }
  }
}

// ---------------- GEMM 256x256, 8 waves, 2-phase counted-vmcnt schedule ----------------
// vTout != null (QKV case): columns >= 2048 are the V projection and are written
// TRANSPOSED directly into vT[(b*16+h)*64+hd][tok].
__global__ __launch_bounds__(512,2) void gemm256(
    const u16* __restrict__ A, const u16* __restrict__ Bt,
    const float* __restrict__ bias0, const float* __restrict__ bias1, const float* __restrict__ bias2,
    float* __restrict__ xres, u16* __restrict__ obf, u16* __restrict__ vTout,
    int M, int N, int K, int epi)
{
  __shared__ u16 As[2][256*64];   // 64 KB
  __shared__ u16 Bs[2][256*64];   // 64 KB
  const int tid = threadIdx.x;
  const int nbx = gridDim.x;
  const int nwg = nbx * gridDim.y;
  int bid = blockIdx.x + nbx*blockIdx.y;
  int nid = (bid & 7)*(nwg >> 3) + (bid >> 3);
  const int bm = (nid % nbx) * 256;
  const int bn = (nid / nbx) * 256;
  const int wv = tid>>6, ln = tid&63;
  const int wm = wv>>2, wn = wv&3;          // 2 x 4 wave grid
  const int l15 = ln&15, lhi = ln>>4;
  const int l8 = ln>>3;
  const int c8s = (ln&7) ^ l8;              // pre-swizzled source chunk

  f32x4 acc[2][2][4][2];
  const f32x4 zero4 = {0.f,0.f,0.f,0.f};
  #pragma unroll
  for (int a=0;a<2;a++)
    #pragma unroll
    for (int b=0;b<2;b++)
      #pragma unroll
      for (int i=0;i<4;i++)
        #pragma unroll
        for (int j=0;j<2;j++) acc[a][b][i][j] = zero4;

  const u16* aB0 = A  + (size_t)(bm + wv*16 + l8)*K + c8s*8;
  const u16* bB0 = Bt + (size_t)(bn + wv*16 + l8)*K + c8s*8;

  #define ISSUE(c, kt) do {                                                  \
    const u16* aB = aB0 + (size_t)(kt)*64;                                   \
    const u16* bB = bB0 + (size_t)(kt)*64;                                   \
    gload16(aB,                 &As[c][(wv*16      )*64]);                   \
    gload16(aB + (size_t)8*K,   &As[c][(wv*16 +   8)*64]);                   \
    gload16(bB,                 &Bs[c][(wv*16      )*64]);                   \
    gload16(bB + (size_t)8*K,   &Bs[c][(wv*16 +   8)*64]);                   \
    gload16(bB + (size_t)128*K, &Bs[c][(128 + wv*16    )*64]);               \
    gload16(bB + (size_t)136*K, &Bs[c][(128 + wv*16 + 8)*64]);               \
    gload16(aB + (size_t)128*K, &As[c][(128 + wv*16    )*64]);               \
    gload16(aB + (size_t)136*K, &As[c][(128 + wv*16 + 8)*64]);               \
  } while(0)

  #define READ_B(c) do {                                                     \
    _Pragma("unroll")                                                        \
    for (int qc=0;qc<2;qc++)                                                 \
      _Pragma("unroll")                                                      \
      for (int j=0;j<2;j++){                                                 \
        int rb = qc*128 + wn*32 + j*16 + l15;                                \
        _Pragma("unroll")                                                    \
        for (int ks=0;ks<2;ks++)                                             \
          bfr[qc][j][ks] = *(const bf16x8*)(&Bs[c][rb*64 + (((ks*4+lhi) ^ (rb&7))<<3)]); \
      }                                                                      \
  } while(0)

  #define READ_A(c, qr) do {                                                 \
    _Pragma("unroll")                                                        \
    for (int i=0;i<4;i++){                                                   \
      int ra = (qr)*128 + wm*64 + i*16 + l15;                                \
      _Pragma("unroll")                                                      \
      for (int ks=0;ks<2;ks++)                                               \
        af[i][ks] = *(const bf16x8*)(&As[c][ra*64 + (((ks*4+lhi) ^ (ra&7))<<3)]); \
    }                                                                        \
  } while(0)

  #define MFMA_Q(qr) do {                                                    \
    __builtin_amdgcn_s_setprio(1);                                           \
    _Pragma("unroll")                                                        \
    for (int ks=0;ks<2;ks++)                                                 \
      _Pragma("unroll")                                                      \
      for (int i=0;i<4;i++)                                                  \
        _Pragma("unroll")                                                    \
        for (int qc=0;qc<2;qc++)                                             \
          _Pragma("unroll")                                                  \
          for (int j=0;j<2;j++)                                              \
            acc[qr][qc][i][j] = __builtin_amdgcn_mfma_f32_16x16x32_bf16(     \
                bfr[qc][j][ks], af[i][ks], acc[qr][qc][i][j], 0,0,0);        \
    __builtin_amdgcn_s_setprio(0);                                           \
  } while(0)

  const int nt = K >> 6;
  ISSUE(0, 0);
  WAITV_BAR(2);
  for (int t=0; t<nt-1; ++t){
    int c = t&1;
    ISSUE(c^1, t+1);
    bf16x8 bfr[2][2][2], af[4][2];
    READ_B(c);
    READ_A(c, 0);
    MFMA_Q(0);
    WAITV_BAR(8);
    READ_A(c, 1);
    MFMA_Q(1);
    WAITV_BAR(2);
  }
  {
    int c = (nt-1)&1;
    bf16x8 bfr[2][2][2], af[4][2];
    READ_B(c);
    READ_A(c, 0);
    MFMA_Q(0);
    WAITV_BAR(0);
    READ_A(c, 1);
    MFMA_Q(1);
  }
  #undef ISSUE
  #undef READ_B
  #undef READ_A
  #undef MFMA_Q

  #pragma unroll
  for (int qc=0; qc<2; qc++)
    #pragma unroll
    for (int j=0;j<2;j++){
      int colbase = bn + qc*128;                 // multiple of 128 -> V test is wave-uniform
      int col0 = colbase + wn*32 + j*16 + lhi*4;
      float4 bv4;
      if (bias1){
        const float* bp = (col0 < 1024) ? (bias0 + col0)
                        : (col0 < 2048) ? (bias1 + col0 - 1024)
                                        : (bias2 + col0 - 2048);
        bv4 = *(const float4*)bp;
      } else {
        bv4 = *(const float4*)(bias0 + col0);
      }
      #pragma unroll
      for (int qr=0; qr<2; qr++)
        #pragma unroll
        for (int i=0;i<4;i++){
          int row = bm + qr*128 + wm*64 + i*16 + l15;
          float v0 = acc[qr][qc][i][j][0]+bv4.x;
          float v1 = acc[qr][qc][i][j][1]+bv4.y;
          float v2 = acc[qr][qc][i][j][2]+bv4.z;
          float v3 = acc[qr][qc][i][j][3]+bv4.w;
          if (vTout && colbase >= 2048){
            int vcol = col0 - 2048;
            int hh = vcol >> 6, hd0 = vcol & 63;
            int bb_ = row >> 11, tk = row & (S_-1);
            u16* vd = vTout + ((size_t)((bb_*16 + hh)*64 + hd0))*S_ + tk;
            vd[0]        = f2b_fast(v0);
            vd[S_]       = f2b_fast(v1);
            vd[2*S_]     = f2b_fast(v2);
            vd[3*(size_t)S_] = f2b_fast(v3);
          } else {
            epi_store(v0, v1, v2, v3, xres, obf, (size_t)row*N + col0, epi);
          }
        }
    }
}

// ---------------- flash attention, KV-split halves, 2-buffer (48 KB -> 3 blocks/CU = 12 waves) ----
// No max-shift softmax -> partials combine additively: store unnormalized
// O_part (bf16) and l_part (f32); attn_combine finishes.
__global__ __launch_bounds__(256) void attn_part(const u16* __restrict__ qkv,
    const u16* __restrict__ vT,
    u16* __restrict__ OpA, u16* __restrict__ OpB,
    float* __restrict__ lpA, float* __restrict__ lpB)
{
  __shared__ u16 Ks[2][64*64];      // 16 KB
  __shared__ u16 Vs[2][64*64];      // 16 KB
  __shared__ u16 Ps[4][2][16*64];   // 16 KB  -> total 48 KB
  const int tid = threadIdx.x, wv = tid>>6, ln = tid&63, l15 = ln&15, lhi = ln>>4;
  const int l8 = ln>>3;
  const int cs = (ln&7) ^ l8;
  int bid = blockIdx.x + 32*(blockIdx.y + 16*blockIdx.z);   // 0..1023
  int nid = (bid & 7)*128 + (bid >> 3);
  const int half = nid & 1;
  const int qt = (nid >> 1) & 15, h = (nid >> 5) & 15, b = nid >> 9;
  const u16* qg = qkv + (size_t)b*S_*3072 + h*64;
  const u16* kg = qg + 1024;
  const u16* vtg = vT + ((size_t)(b*16 + h)*64)*S_;

  bf16x8 qfA[2], qfB[2];
  {
    const u16* qrA = qg + (size_t)(qt*128 + wv*32 + l15)*3072;
    const u16* qrB = qrA + (size_t)16*3072;
    u16 ta[16], tb[16];
    *(uint4*)(ta)   = *(const uint4*)(qrA + lhi*8);
    *(uint4*)(ta+8) = *(const uint4*)(qrA + 32 + lhi*8);
    *(uint4*)(tb)   = *(const uint4*)(qrB + lhi*8);
    *(uint4*)(tb+8) = *(const uint4*)(qrB + 32 + lhi*8);
    #pragma unroll
    for (int i=0;i<16;i++){ ta[i] = f2b_fast(b2f(ta[i]) * 0.18033688f);
                            tb[i] = f2b_fast(b2f(tb[i]) * 0.18033688f); }
    qfA[0] = *(const bf16x8*)(ta); qfA[1] = *(const bf16x8*)(ta+8);
    qfB[0] = *(const bf16x8*)(tb); qfB[1] = *(const bf16x8*)(tb+8);
  }
  const f32x4 zero4 = {0.f,0.f,0.f,0.f};
  f32x4 oaccA[4], oaccB[4];
  #pragma unroll
  for (int j=0;j<4;j++){ oaccA[j] = zero4; oaccB[j] = zero4; }
  float lsumA = 0.f, lsumB = 0.f;

  const int qsw = (l15&7)<<3;
  u16* PsA = &Ps[wv][0][l15*64];
  u16* PsB = &Ps[wv][1][l15*64];

  #define STAGE_KV(bufi, kti) do {                                            \
    _Pragma("unroll")                                                         \
    for (int i_=0;i_<2;i_++){                                                 \
      int r0_ = wv*8 + i_*32;                                                 \
      int row_ = r0_ + l8;                                                    \
      gload16(kg  + (size_t)((kti)*64+row_)*3072 + cs*8, &Ks[bufi][r0_*64]);  \
      gload16(vtg + (size_t)row_*S_ + (kti)*64 + cs*8,   &Vs[bufi][r0_*64]);  \
    }                                                                         \
  } while(0)

  const int kbase = half*16;   // this block handles KV tiles [kbase, kbase+16)
  STAGE_KV(0, kbase);
  WAITV_BAR(0);
  int buf = 0;

  for (int kti=0; kti<16; kti++){
    if (kti+1 < 16) STAGE_KV(buf^1, kbase+kti+1);

    f32x4 sA[4], sB[4];
    __builtin_amdgcn_s_setprio(1);
    #pragma unroll
    for (int j=0;j<4;j++){
      sA[j] = zero4; sB[j] = zero4;
      #pragma unroll
      for (int ks=0; ks<2; ks++){
        int kr = j*16 + l15;
        bf16x8 kf = *(const bf16x8*)(&Ks[buf][kr*64 + (((ks*4+lhi) ^ (kr&7))<<3)]);
        sA[j] = __builtin_amdgcn_mfma_f32_16x16x32_bf16(kf, qfA[ks], sA[j], 0,0,0);
        sB[j] = __builtin_amdgcn_mfma_f32_16x16x32_bf16(kf, qfB[ks], sB[j], 0,0,0);
      }
    }
    __builtin_amdgcn_s_setprio(0);

    float partA = 0.f, partB = 0.f;
    #pragma unroll
    for (int j=0;j<4;j++){
      float a0 = exp2f(sA[j][0]), a1 = exp2f(sA[j][1]), a2 = exp2f(sA[j][2]), a3 = exp2f(sA[j][3]);
      float b0 = exp2f(sB[j][0]), b1 = exp2f(sB[j][1]), b2 = exp2f(sB[j][2]), b3 = exp2f(sB[j][3]);
      partA += (a0+a1)+(a2+a3);
      partB += (b0+b1)+(b2+b3);
      unsigned wA0, wA1, wB0, wB1;
      asm("v_cvt_pk_bf16_f32 %0, %1, %2" : "=v"(wA0) : "v"(a0), "v"(a1));
      asm("v_cvt_pk_bf16_f32 %0, %1, %2" : "=v"(wA1) : "v"(a2), "v"(a3));
      asm("v_cvt_pk_bf16_f32 %0, %1, %2" : "=v"(wB0) : "v"(b0), "v"(b1));
      asm("v_cvt_pk_bf16_f32 %0, %1, %2" : "=v"(wB1) : "v"(b2), "v"(b3));
      int e0 = (j*16 + lhi*4) ^ qsw;
      uint2 wa; wa.x = wA0; wa.y = wA1;
      uint2 wb; wb.x = wB0; wb.y = wB1;
      *(uint2*)(PsA + e0) = wa;
      *(uint2*)(PsB + e0) = wb;
    }
    lsumA += partA; lsumB += partB;

    lds_fence();   // per-wave Ps RAW (no cross-wave barrier needed)

    bf16x8 pfA[2], pfB[2];
    pfA[0] = *(const bf16x8*)(PsA + ((lhi     ^ (l15&7))<<3));
    pfA[1] = *(const bf16x8*)(PsA + (((4+lhi) ^ (l15&7))<<3));
    pfB[0] = *(const bf16x8*)(PsB + ((lhi     ^ (l15&7))<<3));
    pfB[1] = *(const bf16x8*)(PsB + (((4+lhi) ^ (l15&7))<<3));

    __builtin_amdgcn_s_setprio(1);
    #pragma unroll
    for (int dj=0; dj<4; dj++){
      #pragma unroll
      for (int ks=0; ks<2; ks++){
        int vr = dj*16 + l15;
        bf16x8 vf = *(const bf16x8*)(&Vs[buf][vr*64 + (((ks*4+lhi) ^ (vr&7))<<3)]);
        oaccA[dj] = __builtin_amdgcn_mfma_f32_16x16x32_bf16(pfA[ks], vf, oaccA[dj], 0,0,0);
        oaccB[dj] = __builtin_amdgcn_mfma_f32_16x16x32_bf16(pfB[ks], vf, oaccB[dj], 0,0,0);
      }
    }
    __builtin_amdgcn_s_setprio(0);

    WAITV_BAR(0);     // next tile landed; all waves done reading buf (guards overwrite)
    buf ^= 1;
  }
  #undef STAGE_KV

  // per-q totals (no normalization); tot uniform across the 4 lanes sharing l15
  float totA = lsumA + __shfl_xor(lsumA, 16); totA += __shfl_xor(totA, 32);
  float totB = lsumB + __shfl_xor(lsumB, 16); totB += __shfl_xor(totB, 32);

  u16*   Op = half ? OpB : OpA;
  float* lp = half ? lpB : lpA;

  if (lhi == 0){
    int tokA = qt*128 + wv*32 + l15;
    lp[(size_t)(b*S_ + tokA)*16 + h]        = totA;
    lp[(size_t)(b*S_ + tokA + 16)*16 + h]   = totB;
  }

  #pragma unroll
  for (int dj=0; dj<4; dj++){
    #pragma unroll
    for (int r=0;r<4;r++){
      int q = lhi*4 + r;
      int tokA = qt*128 + wv*32 + q;
      int tokB = tokA + 16;
      Op[(size_t)(b*S_ + tokA)*D_ + h*HD_ + dj*16 + l15] = f2b_fast(oaccA[dj][r]);
      Op[(size_t)(b*S_ + tokB)*D_ + h*HD_ + dj*16 + l15] = f2b_fast(oaccB[dj][r]);
    }
  }
}

// ---------------- attn combine: att = (OA + OB) / (lA + lB) ----------------
__global__ __launch_bounds__(256) void attn_combine(
    const u16* __restrict__ OA, const u16* __restrict__ OB,
    const float* __restrict__ lA, const float* __restrict__ lB,
    u16* __restrict__ att)
{
  int tok = blockIdx.x;
  int c0 = threadIdx.x*4;
  int h = c0 >> 6;
  float l = lA[(size_t)tok*16 + h] + lB[(size_t)tok*16 + h];
  float inv = __builtin_amdgcn_rcpf(l);
  uint2 a2 = *(const uint2*)(OA + (size_t)tok*1024 + c0);
  uint2 b2 = *(const uint2*)(OB + (size_t)tok*1024 + c0);
  float a0 = b2f((u16)(a2.x)), a1 = b2f((u16)(a2.x>>16));
  float a2v= b2f((u16)(a2.y)), a3 = b2f((u16)(a2.y>>16));
  float c0v= b2f((u16)(b2.x)), c1 = b2f((u16)(b2.x>>16));
  float c2 = b2f((u16)(b2.y)), c3 = b2f((u16)(b2.y>>16));
  uint2 w;
  w.x = (unsigned)f2b_fast((a0+c0v)*inv) | ((unsigned)f2b_fast((a1+c1)*inv)<<16);
  w.y = (unsigned)f2b_fast((a2v+c2)*inv) | ((unsigned)f2b_fast((a3+c3)*inv)<<16);
  *(uint2*)(att + (size_t)tok*1024 + c0) = w;
}

// ---------------- orchestration ----------------
extern "C" void kernel_launch(void* const* d_in, const int* in_sizes, int n_in,
                              void* d_out, int out_size, void* d_ws, size_t ws_size,
                              hipStream_t stream)
{
  const int*   ids   = (const int*)d_in[0];
  const float* tok   = (const float*)d_in[1];
  const float* pos   = (const float*)d_in[2];
  const float* emb_g = (const float*)d_in[3];
  const float* emb_b = (const float*)d_in[4];
  const float* ln1g  = (const float*)d_in[5];
  const float* ln1b  = (const float*)d_in[6];
  const float* ln2g  = (const float*)d_in[7];
  const float* ln2b  = (const float*)d_in[8];
  const float* Wq = (const float*)d_in[9];
  const float* bq = (const float*)d_in[10];
  const float* Wk = (const float*)d_in[11];
  const float* bk = (const float*)d_in[12];
  const float* Wv = (const float*)d_in[13];
  const float* bv = (const float*)d_in[14];
  const float* Wo = (const float*)d_in[15];
  const float* bo = (const float*)d_in[16];
  const float* W1 = (const float*)d_in[17];
  const float* b1 = (const float*)d_in[18];
  const float* W2 = (const float*)d_in[19];
  const float* b2 = (const float*)d_in[20];

  float* x = (float*)d_out;                    // residual stream lives in d_out (f32)
  char* ws = (char*)d_ws;
  u16* h     = (u16*)(ws);                     //  8 MB
  u16* qkvb  = (u16*)(ws + 8388608);           // 24 MB (V third unused)
  u16* att   = (u16*)(ws + 33554432);          //  8 MB
  u16* fbuf  = (u16*)(ws + 41943040);          // 32 MB (FFN intermediate)
  u16* vT    = fbuf;                           //  8 MB, aliases fbuf head
  u16* OpA   = (u16*)(ws + 50331648);          //  8 MB (attn partials, dead before FFN1)
  u16* OpB   = (u16*)(ws + 58720256);          //  8 MB
  float* lpA = (float*)(ws + 67108864);        //  256 KB
  float* lpB = (float*)(ws + 67371008);        //  256 KB
  u16* wqkvt = (u16*)(ws + 75497472);          //  6 MB
  u16* wot   = (u16*)(ws + 81788928);          //  2 MB
  u16* w1t   = (u16*)(ws + 83886080);          //  8 MB
  u16* w2t   = (u16*)(ws + 92274688);          //  8 MB

  embed_ln<<<NTOK, 256, 0, stream>>>(ids, tok, pos, emb_g, emb_b, x);

  for (int l=0; l<L_; l++){
    ln_f32_bf16<<<NTOK, 256, 0, stream>>>(x, ln1g + l*D_, ln1b + l*D_, h);
    repack_all<<<3072, 256, 0, stream>>>(Wq, Wk, Wv,
        Wo, W1, W2, wqkvt, wot, w1t, w2t, l);
    gemm256<<<dim3(16,12), 512, 0, stream>>>(h, wqkvt,
        bq + l*1024, bk + l*1024, bv + l*1024,
        nullptr, qkvb, vT, NTOK, 3072, 1024, 0);
    attn_part<<<dim3(32,16,2), 256, 0, stream>>>(qkvb, vT, OpA, OpB, lpA, lpB);
    attn_combine<<<NTOK, 256, 0, stream>>>(OpA, OpB, lpA, lpB, att);
    gemm_64x128<<<dim3(64,8), 256, 0, stream>>>(att, wot,
        bo + l*D_, x, NTOK, 1024, 1024);
    ln_f32_bf16<<<NTOK, 256, 0, stream>>>(x, ln2g + l*D_, ln2b + l*D_, h);
    gemm256<<<dim3(16,16), 512, 0, stream>>>(h, w1t,
        b1 + l*F_, nullptr, nullptr,
        nullptr, fbuf, nullptr, NTOK, 4096, 1024, 2);
    gemm_64x128<<<dim3(64,8), 256, 0, stream>>>(fbuf, w2t,
        b2 + l*D_, x, NTOK, 1024, 4096);
  }
}

// Round 23
// 2097.127 us; speedup vs baseline: 1.0235x; 1.0235x over previous
//
#include <hip/hip_runtime.h>
#include <hip/hip_bf16.h>

#define L_ 8
#define H_ 16
#define D_ 1024
#define HD_ 64
#define F_ 4096
#define B_ 2
#define S_ 2048
#define NTOK (B_*S_)

typedef unsigned short u16;
typedef __bf16 bf16x8 __attribute__((ext_vector_type(8)));
typedef float f32x4 __attribute__((ext_vector_type(4)));

__device__ __forceinline__ u16 f2b(float f){ union{float f; unsigned u;} c; c.f = f; unsigned u = c.u; return (u16)((u + 0x7fffu + ((u>>16)&1u)) >> 16); }
__device__ __forceinline__ u16 f2b_fast(float f){ union{float f; unsigned u;} c; c.f = f; return (u16)((c.u + 0x8000u) >> 16); }
__device__ __forceinline__ float b2f(u16 x){ union{unsigned u; float f;} c; c.u = ((unsigned)x)<<16; return c.f; }

__device__ __forceinline__ void gload16(const u16* g, u16* l){
  __builtin_amdgcn_global_load_lds(
      (const __attribute__((address_space(1))) void*)g,
      (__attribute__((address_space(3))) void*)l,
      16 /*bytes*/, 0 /*offset*/, 0 /*aux*/);
}

__device__ __forceinline__ void lds_fence(){
  asm volatile("s_waitcnt lgkmcnt(0)" ::: "memory");
  __builtin_amdgcn_sched_barrier(0);
}

// counted-vmcnt wait + raw barrier (NOT __syncthreads: that drains vmcnt(0))
#define WAITV_BAR(n) do { \
  asm volatile("s_waitcnt vmcnt(%0)" :: "i"(n) : "memory"); \
  __builtin_amdgcn_sched_barrier(0); \
  __builtin_amdgcn_s_barrier(); \
} while(0)

// ---------------- block reduce (256 threads, 4 waves) ----------------
__device__ __forceinline__ void blk_reduce2(float& a, float& b, float* sm){
  for (int off=32; off>0; off>>=1){ a += __shfl_down(a,off); b += __shfl_down(b,off); }
  int w = threadIdx.x>>6, ln = threadIdx.x&63;
  if (ln==0){ sm[w]=a; sm[4+w]=b; }
  __syncthreads();
  a = sm[0]+sm[1]+sm[2]+sm[3];
  b = sm[4]+sm[5]+sm[6]+sm[7];
}

// ---------------- embedding + LN -> x (f32), float4 path ----------------
__global__ __launch_bounds__(256) void embed_ln(const int* __restrict__ ids,
    const float* __restrict__ tok, const float* __restrict__ pos,
    const float* __restrict__ g, const float* __restrict__ bb,
    float* __restrict__ x)
{
  __shared__ float sm[8];
  int row = blockIdx.x;
  int s   = row % S_;
  int id  = ids[row];
  int d0  = threadIdx.x*4;
  float4 t4 = *(const float4*)(tok + (size_t)id*D_ + d0);
  float4 p4 = *(const float4*)(pos + (size_t)s *D_ + d0);
  float4 v; v.x=t4.x+p4.x; v.y=t4.y+p4.y; v.z=t4.z+p4.z; v.w=t4.w+p4.w;
  float sum = (v.x+v.y)+(v.z+v.w);
  float sq  = v.x*v.x+v.y*v.y+v.z*v.z+v.w*v.w;
  blk_reduce2(sum, sq, sm);
  float mean = sum * (1.0f/D_);
  float var  = sq  * (1.0f/D_) - mean*mean;
  float inv  = rsqrtf(var + 1e-5f);
  float4 g4 = *(const float4*)(g + d0);
  float4 b4 = *(const float4*)(bb + d0);
  float4 o; o.x=(v.x-mean)*inv*g4.x+b4.x; o.y=(v.y-mean)*inv*g4.y+b4.y;
            o.z=(v.z-mean)*inv*g4.z+b4.z; o.w=(v.w-mean)*inv*g4.w+b4.w;
  *(float4*)(x + (size_t)row*D_ + d0) = o;
}

// ---------------- LN: x (f32) -> h (bf16), float4 path ----------------
__global__ __launch_bounds__(256) void ln_f32_bf16(const float* __restrict__ x,
    const float* __restrict__ g, const float* __restrict__ bb, u16* __restrict__ out)
{
  __shared__ float sm[8];
  int row = blockIdx.x;
  int d0  = threadIdx.x*4;
  float4 v = *(const float4*)(x + (size_t)row*D_ + d0);
  float sum = (v.x+v.y)+(v.z+v.w);
  float sq  = v.x*v.x+v.y*v.y+v.z*v.z+v.w*v.w;
  blk_reduce2(sum, sq, sm);
  float mean = sum * (1.0f/D_);
  float var  = sq  * (1.0f/D_) - mean*mean;
  float inv  = rsqrtf(var + 1e-5f);
  float4 g4 = *(const float4*)(g + d0);
  float4 b4 = *(const float4*)(bb + d0);
  uint2 w;
  w.x = (unsigned)f2b((v.x-mean)*inv*g4.x+b4.x) | ((unsigned)f2b((v.y-mean)*inv*g4.y+b4.y)<<16);
  w.y = (unsigned)f2b((v.z-mean)*inv*g4.z+b4.z) | ((unsigned)f2b((v.w-mean)*inv*g4.w+b4.w)<<16);
  *(uint2*)(out + (size_t)row*D_ + d0) = w;
}

// ---------------- unified weight repack: all 4 per-layer f32->bf16 transposes ----------------
__global__ __launch_bounds__(256) void repack_all(
    const float* __restrict__ Wq, const float* __restrict__ Wk, const float* __restrict__ Wv,
    const float* __restrict__ Wo, const float* __restrict__ W1, const float* __restrict__ W2,
    u16* __restrict__ wqkvt, u16* __restrict__ wot, u16* __restrict__ w1t, u16* __restrict__ w2t,
    int layer)
{
  __shared__ u16 tile[64*64];
  const int n = blockIdx.x;
  const float* src; u16* dst; int R, C, bx, by;
  if (n < 768){
    int z = n >> 4, xt = n & 15;
    int which = z >> 4, h = z & 15;
    const float* W = (which==0) ? Wq : (which==1) ? Wk : Wv;
    src = W + ((size_t)(layer*H_ + h))*D_*HD_;
    dst = wqkvt + (size_t)(which*1024 + h*64)*D_;
    R = 1024; C = 64; bx = 0; by = xt;
  } else if (n < 1024){
    int q = n - 768;  bx = q & 15; by = q >> 4;
    src = Wo + (size_t)layer*D_*D_;  dst = wot;  R = 1024; C = 1024;
  } else if (n < 2048){
    int q = n - 1024; bx = q & 63; by = q >> 6;
    src = W1 + (size_t)layer*D_*F_;  dst = w1t;  R = 1024; C = 4096;
  } else {
    int q = n - 2048; bx = q & 15; by = q >> 4;
    src = W2 + (size_t)layer*F_*D_;  dst = w2t;  R = 4096; C = 1024;
  }
  int c0 = bx*64, r0 = by*64;
  int t = threadIdx.x;
  #pragma unroll
  for (int i=0;i<2;i++){
    int idx = t + i*256;
    int row = idx>>3, c8 = idx&7;
    const float* p = src + (size_t)(r0+row)*C + c0 + c8*8;
    float4 a = *(const float4*)p;
    float4 b = *(const float4*)(p+4);
    u16 tmp[8];
    tmp[0]=f2b(a.x); tmp[1]=f2b(a.y); tmp[2]=f2b(a.z); tmp[3]=f2b(a.w);
    tmp[4]=f2b(b.x); tmp[5]=f2b(b.y); tmp[6]=f2b(b.z); tmp[7]=f2b(b.w);
    int sw = (row&7) ^ ((row>>3)&7);
    *(uint4*)(&tile[row*64 + ((c8 ^ sw)<<3)]) = *(uint4*)tmp;
  }
  __syncthreads();
  #pragma unroll
  for (int i=0;i<2;i++){
    int idx = t + i*256;
    int oc = idx>>3, tc = idx&7;
    u16 tmp[8];
    #pragma unroll
    for (int j=0;j<8;j++){
      int rr = tc*8 + j;
      int sw = (rr&7) ^ ((rr>>3)&7);
      tmp[j] = tile[rr*64 + ((((oc>>3) ^ sw)<<3) | (oc&7))];
    }
    *(uint4*)(dst + (size_t)(c0+oc)*R + r0 + tc*8) = *(uint4*)tmp;
  }
}

// ---------------- epilogue helper ----------------
__device__ __forceinline__ void epi_store(float v0,float v1,float v2,float v3,
    float* xres, u16* obf, size_t idx, int epi)
{
  if (epi==1){
    float4 t = *(float4*)(xres + idx);
    t.x += v0; t.y += v1; t.z += v2; t.w += v3;
    *(float4*)(xres + idx) = t;
  } else {
    if (epi==2){
      #define GELU_T(v) { float t2=(v)*(v); float u=(v)*fmaf(t2,0.044715f,1.0f); \
                          float e=exp2f(u*-2.3022082f); (v)=(v)*__builtin_amdgcn_rcpf(1.0f+e); }
      GELU_T(v0); GELU_T(v1); GELU_T(v2); GELU_T(v3);
      #undef GELU_T
    }
    uint2 w;
    w.x = (unsigned)f2b_fast(v0) | ((unsigned)f2b_fast(v1) << 16);
    w.y = (unsigned)f2b_fast(v2) | ((unsigned)f2b_fast(v3) << 16);
    *(uint2*)(obf + idx) = w;
  }
}

// ---------------- GEMM 64x128 tile (4 waves of 32x64): residual += A*Bt^T + bias ----------------
__global__ __launch_bounds__(256) void gemm_64x128(
    const u16* __restrict__ A, const u16* __restrict__ Bt,
    const float* __restrict__ bias0, float* __restrict__ xres,
    int M, int N, int K)
{
  __shared__ u16 As[64*64];     //  8 KB
  __shared__ u16 Bs[128*64];    // 16 KB
  const int tid = threadIdx.x;
  const int nbx = gridDim.x;
  const int nwg = nbx * gridDim.y;
  int bid = blockIdx.x + nbx*blockIdx.y;
  int nid = (bid & 7)*(nwg >> 3) + (bid >> 3);
  const int bm = (nid % nbx) * 64;
  const int bn = (nid / nbx) * 128;
  const int wv = tid>>6, ln = tid&63;
  const int wr = wv>>1, wc = wv&1;
  const int l15 = ln&15, lhi = ln>>4;
  const int l8 = ln>>3;
  const int c8s = (ln&7) ^ l8;
  f32x4 acc[2][4];
  const f32x4 zero4 = {0.f,0.f,0.f,0.f};
  #pragma unroll
  for (int i=0;i<2;i++)
    #pragma unroll
    for (int j=0;j<4;j++) acc[i][j] = zero4;

  for (int k0 = 0; k0 < K; k0 += 64) {
    #pragma unroll
    for (int i=0;i<2;i++){
      int row = wv*16 + i*8 + l8;
      gload16(A + (size_t)(bm+row)*K + k0 + c8s*8, &As[(wv*16 + i*8)*64]);
    }
    #pragma unroll
    for (int i=0;i<4;i++){
      int row = wv*32 + i*8 + l8;
      gload16(Bt + (size_t)(bn+row)*K + k0 + c8s*8, &Bs[(wv*32 + i*8)*64]);
    }
    __syncthreads();
    #pragma unroll
    for (int ks=0; ks<2; ks++){
      bf16x8 af[2], bfr[4];
      #pragma unroll
      for (int i=0;i<2;i++){
        int ra = wr*32 + i*16 + l15;
        af[i]  = *(const bf16x8*)(&As[ra*64 + (((ks*4+lhi) ^ (ra&7))<<3)]);
      }
      #pragma unroll
      for (int j=0;j<4;j++){
        int rb = wc*64 + j*16 + l15;
        bfr[j] = *(const bf16x8*)(&Bs[rb*64 + (((ks*4+lhi) ^ (rb&7))<<3)]);
      }
      #pragma unroll
      for (int i=0;i<2;i++)
        #pragma unroll
        for (int j=0;j<4;j++)
          acc[i][j] = __builtin_amdgcn_mfma_f32_16x16x32_bf16(bfr[j], af[i], acc[i][j], 0,0,0);
    }
    __syncthreads();
  }

  #pragma unroll
  for (int j=0;j<4;j++){
    int col0 = bn + wc*64 + j*16 + lhi*4;
    float4 bv4 = *(const float4*)(bias0 + col0);
    #pragma unroll
    for (int i=0;i<2;i++){
      int row = bm + wr*32 + i*16 + l15;
      size_t idx = (size_t)row*N + col0;
      float4 t = *(float4*)(xres + idx);
      t.x += acc[i][j][0] + bv4.x;
      t.y += acc[i][j][1] + bv4.y;
      t.z += acc[i][j][2] + bv4.z;
      t.w += acc[i][j][3] + bv4.w;
      *(float4*)(xres + idx) = t;
    }
  }
}

// ---------------- GEMM 256x256, 8 waves, 2-phase counted-vmcnt schedule ----------------
// vTout != null (QKV case): columns >= 2048 are the V projection and are written
// TRANSPOSED directly into vT[(b*16+h)*64+hd][tok].
__global__ __launch_bounds__(512,2) void gemm256(
    const u16* __restrict__ A, const u16* __restrict__ Bt,
    const float* __restrict__ bias0, const float* __restrict__ bias1, const float* __restrict__ bias2,
    float* __restrict__ xres, u16* __restrict__ obf, u16* __restrict__ vTout,
    int M, int N, int K, int epi)
{
  __shared__ u16 As[2][256*64];   // 64 KB
  __shared__ u16 Bs[2][256*64];   // 64 KB
  const int tid = threadIdx.x;
  const int nbx = gridDim.x;
  const int nwg = nbx * gridDim.y;
  int bid = blockIdx.x + nbx*blockIdx.y;
  int nid = (bid & 7)*(nwg >> 3) + (bid >> 3);
  const int bm = (nid % nbx) * 256;
  const int bn = (nid / nbx) * 256;
  const int wv = tid>>6, ln = tid&63;
  const int wm = wv>>2, wn = wv&3;          // 2 x 4 wave grid
  const int l15 = ln&15, lhi = ln>>4;
  const int l8 = ln>>3;
  const int c8s = (ln&7) ^ l8;              // pre-swizzled source chunk

  f32x4 acc[2][2][4][2];
  const f32x4 zero4 = {0.f,0.f,0.f,0.f};
  #pragma unroll
  for (int a=0;a<2;a++)
    #pragma unroll
    for (int b=0;b<2;b++)
      #pragma unroll
      for (int i=0;i<4;i++)
        #pragma unroll
        for (int j=0;j<2;j++) acc[a][b][i][j] = zero4;

  const u16* aB0 = A  + (size_t)(bm + wv*16 + l8)*K + c8s*8;
  const u16* bB0 = Bt + (size_t)(bn + wv*16 + l8)*K + c8s*8;

  #define ISSUE(c, kt) do {                                                  \
    const u16* aB = aB0 + (size_t)(kt)*64;                                   \
    const u16* bB = bB0 + (size_t)(kt)*64;                                   \
    gload16(aB,                 &As[c][(wv*16      )*64]);                   \
    gload16(aB + (size_t)8*K,   &As[c][(wv*16 +   8)*64]);                   \
    gload16(bB,                 &Bs[c][(wv*16      )*64]);                   \
    gload16(bB + (size_t)8*K,   &Bs[c][(wv*16 +   8)*64]);                   \
    gload16(bB + (size_t)128*K, &Bs[c][(128 + wv*16    )*64]);               \
    gload16(bB + (size_t)136*K, &Bs[c][(128 + wv*16 + 8)*64]);               \
    gload16(aB + (size_t)128*K, &As[c][(128 + wv*16    )*64]);               \
    gload16(aB + (size_t)136*K, &As[c][(128 + wv*16 + 8)*64]);               \
  } while(0)

  #define READ_B(c) do {                                                     \
    _Pragma("unroll")                                                        \
    for (int qc=0;qc<2;qc++)                                                 \
      _Pragma("unroll")                                                      \
      for (int j=0;j<2;j++){                                                 \
        int rb = qc*128 + wn*32 + j*16 + l15;                                \
        _Pragma("unroll")                                                    \
        for (int ks=0;ks<2;ks++)                                             \
          bfr[qc][j][ks] = *(const bf16x8*)(&Bs[c][rb*64 + (((ks*4+lhi) ^ (rb&7))<<3)]); \
      }                                                                      \
  } while(0)

  #define READ_A(c, qr) do {                                                 \
    _Pragma("unroll")                                                        \
    for (int i=0;i<4;i++){                                                   \
      int ra = (qr)*128 + wm*64 + i*16 + l15;                                \
      _Pragma("unroll")                                                      \
      for (int ks=0;ks<2;ks++)                                               \
        af[i][ks] = *(const bf16x8*)(&As[c][ra*64 + (((ks*4+lhi) ^ (ra&7))<<3)]); \
    }                                                                        \
  } while(0)

  #define MFMA_Q(qr) do {                                                    \
    __builtin_amdgcn_s_setprio(1);                                           \
    _Pragma("unroll")                                                        \
    for (int ks=0;ks<2;ks++)                                                 \
      _Pragma("unroll")                                                      \
      for (int i=0;i<4;i++)                                                  \
        _Pragma("unroll")                                                    \
        for (int qc=0;qc<2;qc++)                                             \
          _Pragma("unroll")                                                  \
          for (int j=0;j<2;j++)                                              \
            acc[qr][qc][i][j] = __builtin_amdgcn_mfma_f32_16x16x32_bf16(     \
                bfr[qc][j][ks], af[i][ks], acc[qr][qc][i][j], 0,0,0);        \
    __builtin_amdgcn_s_setprio(0);                                           \
  } while(0)

  const int nt = K >> 6;
  ISSUE(0, 0);
  WAITV_BAR(2);
  for (int t=0; t<nt-1; ++t){
    int c = t&1;
    ISSUE(c^1, t+1);
    bf16x8 bfr[2][2][2], af[4][2];
    READ_B(c);
    READ_A(c, 0);
    MFMA_Q(0);
    WAITV_BAR(8);
    READ_A(c, 1);
    MFMA_Q(1);
    WAITV_BAR(2);
  }
  {
    int c = (nt-1)&1;
    bf16x8 bfr[2][2][2], af[4][2];
    READ_B(c);
    READ_A(c, 0);
    MFMA_Q(0);
    WAITV_BAR(0);
    READ_A(c, 1);
    MFMA_Q(1);
  }
  #undef ISSUE
  #undef READ_B
  #undef READ_A
  #undef MFMA_Q

  #pragma unroll
  for (int qc=0; qc<2; qc++)
    #pragma unroll
    for (int j=0;j<2;j++){
      int colbase = bn + qc*128;                 // multiple of 128 -> V test is wave-uniform
      int col0 = colbase + wn*32 + j*16 + lhi*4;
      float4 bv4;
      if (bias1){
        const float* bp = (col0 < 1024) ? (bias0 + col0)
                        : (col0 < 2048) ? (bias1 + col0 - 1024)
                                        : (bias2 + col0 - 2048);
        bv4 = *(const float4*)bp;
      } else {
        bv4 = *(const float4*)(bias0 + col0);
      }
      #pragma unroll
      for (int qr=0; qr<2; qr++)
        #pragma unroll
        for (int i=0;i<4;i++){
          int row = bm + qr*128 + wm*64 + i*16 + l15;
          float v0 = acc[qr][qc][i][j][0]+bv4.x;
          float v1 = acc[qr][qc][i][j][1]+bv4.y;
          float v2 = acc[qr][qc][i][j][2]+bv4.z;
          float v3 = acc[qr][qc][i][j][3]+bv4.w;
          if (vTout && colbase >= 2048){
            int vcol = col0 - 2048;
            int hh = vcol >> 6, hd0 = vcol & 63;
            int bb_ = row >> 11, tk = row & (S_-1);
            u16* vd = vTout + ((size_t)((bb_*16 + hh)*64 + hd0))*S_ + tk;
            vd[0]        = f2b_fast(v0);
            vd[S_]       = f2b_fast(v1);
            vd[2*S_]     = f2b_fast(v2);
            vd[3*(size_t)S_] = f2b_fast(v3);
          } else {
            epi_store(v0, v1, v2, v3, xres, obf, (size_t)row*N + col0, epi);
          }
        }
    }
}

// ---------------- flash attention: 3-buffer 2-deep prefetch, counted vmcnt ----------------
__global__ __launch_bounds__(256) void attn_fwd(const u16* __restrict__ qkv,
    const u16* __restrict__ vT, u16* __restrict__ att)
{
  __shared__ u16 Ks[3][64*64];      // 24 KB
  __shared__ u16 Vs[3][64*64];      // 24 KB
  __shared__ u16 Ps[4][2][16*64];   // 16 KB
  const int tid = threadIdx.x, wv = tid>>6, ln = tid&63, l15 = ln&15, lhi = ln>>4;
  const int l8 = ln>>3;
  const int cs = (ln&7) ^ l8;
  int bid = blockIdx.x + 16*(blockIdx.y + 16*blockIdx.z);
  int nid = (bid & 7)*64 + (bid >> 3);
  const int qt = nid & 15, h = (nid >> 4) & 15, b = nid >> 8;
  const u16* qg = qkv + (size_t)b*S_*3072 + h*64;
  const u16* kg = qg + 1024;
  const u16* vtg = vT + ((size_t)(b*16 + h)*64)*S_;

  bf16x8 qfA[2], qfB[2];
  {
    const u16* qrA = qg + (size_t)(qt*128 + wv*32 + l15)*3072;
    const u16* qrB = qrA + (size_t)16*3072;
    u16 ta[16], tb[16];
    *(uint4*)(ta)   = *(const uint4*)(qrA + lhi*8);
    *(uint4*)(ta+8) = *(const uint4*)(qrA + 32 + lhi*8);
    *(uint4*)(tb)   = *(const uint4*)(qrB + lhi*8);
    *(uint4*)(tb+8) = *(const uint4*)(qrB + 32 + lhi*8);
    #pragma unroll
    for (int i=0;i<16;i++){ ta[i] = f2b_fast(b2f(ta[i]) * 0.18033688f);
                            tb[i] = f2b_fast(b2f(tb[i]) * 0.18033688f); }
    qfA[0] = *(const bf16x8*)(ta); qfA[1] = *(const bf16x8*)(ta+8);
    qfB[0] = *(const bf16x8*)(tb); qfB[1] = *(const bf16x8*)(tb+8);
  }
  const f32x4 zero4 = {0.f,0.f,0.f,0.f};
  f32x4 oaccA[4], oaccB[4];
  #pragma unroll
  for (int j=0;j<4;j++){ oaccA[j] = zero4; oaccB[j] = zero4; }
  float lsumA = 0.f, lsumB = 0.f;

  const int qsw = (l15&7)<<3;                  // XOR for this lane's q row
  u16* PsA = &Ps[wv][0][l15*64];
  u16* PsB = &Ps[wv][1][l15*64];

  #define STAGE_KV(bufi, kti) do {                                            \
    _Pragma("unroll")                                                         \
    for (int i_=0;i_<2;i_++){                                                 \
      int r0_ = wv*8 + i_*32;                                                 \
      int row_ = r0_ + l8;                                                    \
      gload16(kg  + (size_t)((kti)*64+row_)*3072 + cs*8, &Ks[bufi][r0_*64]);  \
      gload16(vtg + (size_t)row_*S_ + (kti)*64 + cs*8,   &Vs[bufi][r0_*64]);  \
    }                                                                         \
  } while(0)

  STAGE_KV(0, 0);
  STAGE_KV(1, 1);
  WAITV_BAR(4);          // kt0 landed; kt1's 4 loads in flight
  int cur = 0;

  const int NT = S_/64;
  for (int kt=0; kt<NT; kt++){
    int nxt2 = cur + 2; if (nxt2 >= 3) nxt2 -= 3;
    if (kt+2 < NT) STAGE_KV(nxt2, kt+2);

    f32x4 sA[4], sB[4];
    __builtin_amdgcn_s_setprio(1);
    #pragma unroll
    for (int j=0;j<4;j++){
      sA[j] = zero4; sB[j] = zero4;
      #pragma unroll
      for (int ks=0; ks<2; ks++){
        int kr = j*16 + l15;
        bf16x8 kf = *(const bf16x8*)(&Ks[cur][kr*64 + (((ks*4+lhi) ^ (kr&7))<<3)]);
        sA[j] = __builtin_amdgcn_mfma_f32_16x16x32_bf16(kf, qfA[ks], sA[j], 0,0,0);
        sB[j] = __builtin_amdgcn_mfma_f32_16x16x32_bf16(kf, qfB[ks], sB[j], 0,0,0);
      }
    }
    __builtin_amdgcn_s_setprio(0);

    float partA = 0.f, partB = 0.f;
    #pragma unroll
    for (int j=0;j<4;j++){
      float a0 = exp2f(sA[j][0]), a1 = exp2f(sA[j][1]), a2 = exp2f(sA[j][2]), a3 = exp2f(sA[j][3]);
      float b0 = exp2f(sB[j][0]), b1 = exp2f(sB[j][1]), b2 = exp2f(sB[j][2]), b3 = exp2f(sB[j][3]);
      partA += (a0+a1)+(a2+a3);
      partB += (b0+b1)+(b2+b3);
      unsigned wA0, wA1, wB0, wB1;
      asm("v_cvt_pk_bf16_f32 %0, %1, %2" : "=v"(wA0) : "v"(a0), "v"(a1));
      asm("v_cvt_pk_bf16_f32 %0, %1, %2" : "=v"(wA1) : "v"(a2), "v"(a3));
      asm("v_cvt_pk_bf16_f32 %0, %1, %2" : "=v"(wB0) : "v"(b0), "v"(b1));
      asm("v_cvt_pk_bf16_f32 %0, %1, %2" : "=v"(wB1) : "v"(b2), "v"(b3));
      int e0 = (j*16 + lhi*4) ^ qsw;
      uint2 wa; wa.x = wA0; wa.y = wA1;
      uint2 wb; wb.x = wB0; wb.y = wB1;
      *(uint2*)(PsA + e0) = wa;
      *(uint2*)(PsB + e0) = wb;
    }
    lsumA += partA; lsumB += partB;

    lds_fence();   // per-wave Ps RAW (no cross-wave barrier needed)

    bf16x8 pfA[2], pfB[2];
    pfA[0] = *(const bf16x8*)(PsA + ((lhi     ^ (l15&7))<<3));
    pfA[1] = *(const bf16x8*)(PsA + (((4+lhi) ^ (l15&7))<<3));
    pfB[0] = *(const bf16x8*)(PsB + ((lhi     ^ (l15&7))<<3));
    pfB[1] = *(const bf16x8*)(PsB + (((4+lhi) ^ (l15&7))<<3));

    __builtin_amdgcn_s_setprio(1);
    #pragma unroll
    for (int dj=0; dj<4; dj++){
      #pragma unroll
      for (int ks=0; ks<2; ks++){
        int vr = dj*16 + l15;
        bf16x8 vf = *(const bf16x8*)(&Vs[cur][vr*64 + (((ks*4+lhi) ^ (vr&7))<<3)]);
        oaccA[dj] = __builtin_amdgcn_mfma_f32_16x16x32_bf16(pfA[ks], vf, oaccA[dj], 0,0,0);
        oaccB[dj] = __builtin_amdgcn_mfma_f32_16x16x32_bf16(pfB[ks], vf, oaccB[dj], 0,0,0);
      }
    }
    __builtin_amdgcn_s_setprio(0);

    if (kt+2 < NT) { WAITV_BAR(4); }
    else           { WAITV_BAR(0); }
    cur = (cur==2) ? 0 : cur+1;
  }
  #undef STAGE_KV

  float totA = lsumA + __shfl_xor(lsumA, 16); totA += __shfl_xor(totA, 32);
  float totB = lsumB + __shfl_xor(lsumB, 16); totB += __shfl_xor(totB, 32);
  float invA[4], invB[4];
  #pragma unroll
  for (int r=0;r<4;r++){
    invA[r] = __builtin_amdgcn_rcpf(__shfl(totA, lhi*4+r));
    invB[r] = __builtin_amdgcn_rcpf(__shfl(totB, lhi*4+r));
  }

  #pragma unroll
  for (int dj=0; dj<4; dj++){
    #pragma unroll
    for (int r=0;r<4;r++){
      int q = lhi*4 + r;
      int tokA = qt*128 + wv*32 + q;
      int tokB = tokA + 16;
      att[(size_t)(b*S_ + tokA)*D_ + h*HD_ + dj*16 + l15] = f2b_fast(oaccA[dj][r] * invA[r]);
      att[(size_t)(b*S_ + tokB)*D_ + h*HD_ + dj*16 + l15] = f2b_fast(oaccB[dj][r] * invB[r]);
    }
  }
}

// ---------------- orchestration ----------------
extern "C" void kernel_launch(void* const* d_in, const int* in_sizes, int n_in,
                              void* d_out, int out_size, void* d_ws, size_t ws_size,
                              hipStream_t stream)
{
  const int*   ids   = (const int*)d_in[0];
  const float* tok   = (const float*)d_in[1];
  const float* pos   = (const float*)d_in[2];
  const float* emb_g = (const float*)d_in[3];
  const float* emb_b = (const float*)d_in[4];
  const float* ln1g  = (const float*)d_in[5];
  const float* ln1b  = (const float*)d_in[6];
  const float* ln2g  = (const float*)d_in[7];
  const float* ln2b  = (const float*)d_in[8];
  const float* Wq = (const float*)d_in[9];
  const float* bq = (const float*)d_in[10];
  const float* Wk = (const float*)d_in[11];
  const float* bk = (const float*)d_in[12];
  const float* Wv = (const float*)d_in[13];
  const float* bv = (const float*)d_in[14];
  const float* Wo = (const float*)d_in[15];
  const float* bo = (const float*)d_in[16];
  const float* W1 = (const float*)d_in[17];
  const float* b1 = (const float*)d_in[18];
  const float* W2 = (const float*)d_in[19];
  const float* b2 = (const float*)d_in[20];

  float* x = (float*)d_out;                    // residual stream lives in d_out (f32)
  char* ws = (char*)d_ws;
  u16* h     = (u16*)(ws);                     //  8 MB
  u16* qkvb  = (u16*)(ws + 8388608);           // 24 MB (V third unused)
  u16* att   = (u16*)(ws + 33554432);          //  8 MB
  u16* fbuf  = (u16*)(ws + 41943040);          // 32 MB (FFN intermediate)
  u16* vT    = fbuf;                           //  8 MB, aliases fbuf head
  u16* wqkvt = (u16*)(ws + 75497472);          //  6 MB
  u16* wot   = (u16*)(ws + 81788928);          //  2 MB
  u16* w1t   = (u16*)(ws + 83886080);          //  8 MB
  u16* w2t   = (u16*)(ws + 92274688);          //  8 MB

  embed_ln<<<NTOK, 256, 0, stream>>>(ids, tok, pos, emb_g, emb_b, x);

  for (int l=0; l<L_; l++){
    ln_f32_bf16<<<NTOK, 256, 0, stream>>>(x, ln1g + l*D_, ln1b + l*D_, h);
    repack_all<<<3072, 256, 0, stream>>>(Wq, Wk, Wv,
        Wo, W1, W2, wqkvt, wot, w1t, w2t, l);
    gemm256<<<dim3(16,12), 512, 0, stream>>>(h, wqkvt,
        bq + l*1024, bk + l*1024, bv + l*1024,
        nullptr, qkvb, vT, NTOK, 3072, 1024, 0);
    attn_fwd<<<dim3(S_/128, H_, B_), 256, 0, stream>>>(qkvb, vT, att);
    gemm_64x128<<<dim3(64,8), 256, 0, stream>>>(att, wot,
        bo + l*D_, x, NTOK, 1024, 1024);
    ln_f32_bf16<<<NTOK, 256, 0, stream>>>(x, ln2g + l*D_, ln2b + l*D_, h);
    gemm256<<<dim3(16,16), 512, 0, stream>>>(h, w1t,
        b1 + l*F_, nullptr, nullptr,
        nullptr, fbuf, nullptr, NTOK, 4096, 1024, 2);
    gemm_64x128<<<dim3(64,8), 256, 0, stream>>>(fbuf, w2t,
        b2 + l*D_, x, NTOK, 1024, 4096);
  }
}